// Round 15
// baseline (1530.985 us; speedup 1.0000x reference)
//
#include <hip/hip_runtime.h>
#include <hip/hip_cooperative_groups.h>
#include <hip/hip_fp16.h>
#include <math.h>

#define BN_EPS 1e-5f
#define NHB 128  // hist-owner blocks

namespace cg = cooperative_groups;

union H8 {  // 8 halfs = 16 bytes
  float4 f4;
  __half2 h2[4];
};

union SMem {
  struct { int h[512]; } hist;
  struct { int ps[256]; } scan;
  struct { int h[512]; int base[512]; } part;
  struct { int lcnt[256]; int lpre[256]; float w1s[64]; } fill;
  struct { float w[2048]; float bsc[32]; float bsh[32]; } mm;
  struct { float redS[2048]; float redQ[2048]; } red;
};

// ---- gather (fp16 rows) + bias + ReLU -> fp16 act; block-local stats in regs ----
template <int C, int LOGGP>
__device__ void gather_phase(const float4* __restrict__ hh8, const int* __restrict__ row_start,
                             const int* __restrict__ csr_src, const float* __restrict__ dinv,
                             const float* __restrict__ bias, float4* __restrict__ act4,
                             float* __restrict__ partials, int n,
                             float* redS, float* redQ) {
  constexpr int GP = C / 8;
  constexpr int NPB = 256 / GP;
  int tid = threadIdx.x;
  int c8 = tid & (GP - 1);
  int local = tid >> LOGGP;
  float lsum[8], lsq[8];
#pragma unroll
  for (int t = 0; t < 8; t++) { lsum[t] = 0.f; lsq[t] = 0.f; }

  const float4* bias4 = (const float4*)bias;
  float4 blo = bias4[c8 * 2], bhi = bias4[c8 * 2 + 1];
  float bb[8] = {blo.x, blo.y, blo.z, blo.w, bhi.x, bhi.y, bhi.z, bhi.w};

  int ngrp = (n + NPB - 1) / NPB;
  for (int grp = blockIdx.x; grp < ngrp; grp += gridDim.x) {
    int n0 = grp * NPB + local;
    if (n0 >= n) continue;
    float acc[8];
    {
      H8 u;
      u.f4 = hh8[(size_t)n0 * GP + c8];  // self term
#pragma unroll
      for (int q = 0; q < 4; q++) {
        float2 f = __half22float2(u.h2[q]);
        acc[2 * q] = f.x;
        acc[2 * q + 1] = f.y;
      }
    }
    int s = row_start[n0], e0 = row_start[n0 + 1];
    int j = s;
    for (; j + 4 <= e0; j += 4) {
      H8 u0, u1, u2, u3;
      u0.f4 = hh8[(size_t)csr_src[j] * GP + c8];
      u1.f4 = hh8[(size_t)csr_src[j + 1] * GP + c8];
      u2.f4 = hh8[(size_t)csr_src[j + 2] * GP + c8];
      u3.f4 = hh8[(size_t)csr_src[j + 3] * GP + c8];
#pragma unroll
      for (int q = 0; q < 4; q++) {
        float2 f0 = __half22float2(u0.h2[q]), f1 = __half22float2(u1.h2[q]);
        float2 f2 = __half22float2(u2.h2[q]), f3 = __half22float2(u3.h2[q]);
        acc[2 * q] += (f0.x + f1.x) + (f2.x + f3.x);
        acc[2 * q + 1] += (f0.y + f1.y) + (f2.y + f3.y);
      }
    }
    for (; j < e0; j++) {
      H8 u;
      u.f4 = hh8[(size_t)csr_src[j] * GP + c8];
#pragma unroll
      for (int q = 0; q < 4; q++) {
        float2 f = __half22float2(u.h2[q]);
        acc[2 * q] += f.x;
        acc[2 * q + 1] += f.y;
      }
    }
    float dn = dinv[n0];
    H8 o;
#pragma unroll
    for (int q = 0; q < 4; q++) {
      float v0 = fmaxf(dn * acc[2 * q] + bb[2 * q], 0.f);
      float v1 = fmaxf(dn * acc[2 * q + 1] + bb[2 * q + 1], 0.f);
      lsum[2 * q] += v0;     lsq[2 * q] += v0 * v0;
      lsum[2 * q + 1] += v1; lsq[2 * q + 1] += v1 * v1;
      o.h2[q] = __float22half2_rn(make_float2(v0, v1));
    }
    act4[(size_t)n0 * GP + c8] = o.f4;
  }

  // block reduce over 'local' -> partials[bid*128 + ch] (sum), [.. + C + ch] (sumsq)
#pragma unroll
  for (int t = 0; t < 8; t++) {
    redS[t * 256 + tid] = lsum[t];
    redQ[t * 256 + tid] = lsq[t];
  }
#pragma unroll
  for (int off = NPB / 2; off >= 1; off >>= 1) {
    __syncthreads();
    if (local < off) {
#pragma unroll
      for (int t = 0; t < 8; t++) {
        redS[t * 256 + tid] += redS[t * 256 + tid + off * GP];
        redQ[t * 256 + tid] += redQ[t * 256 + tid + off * GP];
      }
    }
  }
  __syncthreads();
  if (local == 0) {
#pragma unroll
    for (int t = 0; t < 8; t++) {
      partials[(size_t)blockIdx.x * 128 + c8 * 8 + t] = redS[t * 256 + tid];
      partials[(size_t)blockIdx.x * 128 + C + c8 * 8 + t] = redQ[t * 256 + tid];
    }
  }
  __syncthreads();
}

// owner-write reduce: block ch (< C2) sums partials[.][ch] -> statsL[ch]
__device__ void reduce_phase(const float* __restrict__ partials, float* __restrict__ statsL,
                             int C2, int nblk, float* red) {
  int tid = threadIdx.x;
  if ((int)blockIdx.x < C2) {
    float acc = 0.f;
    for (int r = tid; r < nblk; r += 256) acc += partials[(size_t)r * 128 + blockIdx.x];
    red[tid] = acc;
    __syncthreads();
#pragma unroll
    for (int off = 128; off >= 1; off >>= 1) {
      if (tid < off) red[tid] += red[tid + off];
      __syncthreads();
    }
    if (tid == 0) statsL[blockIdx.x] = red[0];
  }
}

// ---- fused BN+ELU+matmul (fp16 in) -> fp16 hh ----
template <int K, int C>
__device__ void mm_phase(const float4* __restrict__ Xh, const float* __restrict__ stats,
                         const float* __restrict__ g, const float* __restrict__ bt,
                         const float* __restrict__ W, const float* __restrict__ dinv,
                         float4* __restrict__ hh, int n,
                         float* w, float* bsc, float* bsh) {
  constexpr int GP8 = C / 8;
  constexpr int KG8 = K / 8;
  int tid = threadIdx.x;
  for (int i = tid; i < K * C; i += 256) w[i] = W[i];
  if (tid < K) {
    float inv_n = 1.0f / (float)n;
    float m = stats[tid] * inv_n;
    float var = fmaxf(stats[K + tid] * inv_n - m * m, 0.f);
    float sc = rsqrtf(var + BN_EPS) * g[tid];
    bsc[tid] = sc;
    bsh[tid] = bt[tid] - m * sc;
  }
  __syncthreads();
  for (int idx = blockIdx.x * 256 + tid; idx < n * GP8; idx += gridDim.x * 256) {
    int nn = idx / GP8;
    int c8 = idx % GP8;
    float acc[8];
#pragma unroll
    for (int t = 0; t < 8; t++) acc[t] = 0.f;
    const float4* rowh = Xh + (size_t)nn * KG8;
#pragma unroll
    for (int j8 = 0; j8 < KG8; j8++) {
      H8 u;
      u.f4 = rowh[j8];
#pragma unroll
      for (int q = 0; q < 4; q++) {
        float2 f = __half22float2(u.h2[q]);
        int k0 = j8 * 8 + 2 * q, k1 = k0 + 1;
        float v0 = f.x * bsc[k0] + bsh[k0];
        v0 = v0 > 0.f ? v0 : (__expf(v0) - 1.f);
        float v1 = f.y * bsc[k1] + bsh[k1];
        v1 = v1 > 0.f ? v1 : (__expf(v1) - 1.f);
        int wb0 = k0 * C + c8 * 8, wb1 = k1 * C + c8 * 8;
#pragma unroll
        for (int t = 0; t < 8; t++) acc[t] += v0 * w[wb0 + t] + v1 * w[wb1 + t];
      }
    }
    float dn = dinv[nn];
    H8 o;
#pragma unroll
    for (int q = 0; q < 4; q++)
      o.h2[q] = __float22half2_rn(make_float2(acc[2 * q] * dn, acc[2 * q + 1] * dn));
    hh[idx] = o.f4;
  }
  __syncthreads();
}

// ================= mega kernel: CSR build + 3 GCN layers =================
__global__ __launch_bounds__(256, 8) void gcn_mega(
    const float* x, const int* srcp, const int* dstp,
    const float* W1, const float* b1, const float* g1, const float* bt1,
    const float* W2, const float* b2, const float* g2, const float* bt2,
    const float* W3, const float* b3, const float* g3, const float* bt3,
    float* dinv, int* row_start, int* histpart, float* stats,
    int* boffset, int* bcursor, int* csr_src, float* partials,
    float4* bufH, float4* bufAct, int* ebuf, int n, int e, int nbuck) {
  cg::grid_group grid = cg::this_grid();
  __shared__ SMem sm;
  int tid = threadIdx.x;
  int bid = blockIdx.x;
  int nblk = gridDim.x;

  // P0: per-block histograms (NHB owner blocks)
  if (bid < NHB) {
    for (int i = tid; i < 512; i += 256) sm.hist.h[i] = 0;
    __syncthreads();
    for (int i = bid * 256 + tid; i < e; i += NHB * 256)
      atomicAdd(&sm.hist.h[dstp[i] >> 8], 1);
    __syncthreads();
    for (int i = tid; i < 512; i += 256) histpart[bid * 512 + i] = sm.hist.h[i];
  }
  grid.sync();

  // P1: scan (block 0): column-sum 512 buckets (2 per thread) + pair scan
  if (bid == 0) {
    int b0 = 2 * tid, b1i = 2 * tid + 1;
    int v0 = 0, v1 = 0;
    for (int r = 0; r < NHB; r++) {
      v0 += histpart[r * 512 + b0];
      v1 += histpart[r * 512 + b1i];
    }
    int pair = v0 + v1;
    sm.scan.ps[tid] = pair;
    __syncthreads();
    for (int off = 1; off < 256; off <<= 1) {
      int add = (tid >= off) ? sm.scan.ps[tid - off] : 0;
      __syncthreads();
      sm.scan.ps[tid] += add;
      __syncthreads();
    }
    int excl = sm.scan.ps[tid] - pair;
    boffset[b0] = excl;      bcursor[b0] = excl;
    boffset[b1i] = excl + v0; bcursor[b1i] = excl + v0;
    if (tid == 255) { boffset[512] = e; bcursor[512] = e; row_start[n] = e; }
  }
  grid.sync();

  // P2: partition into bucketed ebuf (packed src<<8 | dst&255)
  int nchunks = (e + 4095) >> 12;
  for (int c = bid; c < nchunks; c += nblk) {
    int e0 = c << 12, e1 = min(e0 + 4096, e);
    for (int i = tid; i < 512; i += 256) sm.part.h[i] = 0;
    __syncthreads();
    for (int i = e0 + tid; i < e1; i += 256)
      atomicAdd(&sm.part.h[dstp[i] >> 8], 1);
    __syncthreads();
    for (int i = tid; i < 512; i += 256) {
      int cc = sm.part.h[i];
      sm.part.base[i] = (cc > 0) ? atomicAdd(&bcursor[i], cc) : 0;
      sm.part.h[i] = 0;
    }
    __syncthreads();
    for (int i = e0 + tid; i < e1; i += 256) {
      int d = dstp[i];
      int b = d >> 8;
      int r = atomicAdd(&sm.part.h[b], 1);
      ebuf[sm.part.base[b] + r] = (srcp[i] << 8) | (d & 255);
    }
    __syncthreads();
  }
  grid.sync();

  // P3: bucket fill -> row_start, dinv, csr_src; fused hh1 = fp16(dinv*x@W1)
  for (int b = bid; b < nbuck; b += nblk) {
    int nb0 = b << 8;
    int e0 = boffset[b], e1 = boffset[b + 1];
    sm.fill.lcnt[tid] = 0;
    if (tid < 64) sm.fill.w1s[tid] = W1[tid];
    __syncthreads();
    for (int j = e0 + tid; j < e1; j += 256)
      atomicAdd(&sm.fill.lcnt[ebuf[j] & 255], 1);
    __syncthreads();
    int v = sm.fill.lcnt[tid];
    sm.fill.lpre[tid] = v;
    __syncthreads();
    for (int off = 1; off < 256; off <<= 1) {
      int add = (tid >= off) ? sm.fill.lpre[tid - off] : 0;
      __syncthreads();
      sm.fill.lpre[tid] += add;
      __syncthreads();
    }
    int excl = sm.fill.lpre[tid] - v;
    int node = nb0 + tid;
    if (node < n) {
      row_start[node] = e0 + excl;
      float dnv = rsqrtf((float)(v + 1));
      dinv[node] = dnv;
      float4 xr = ((const float4*)x)[node];
      float acc[16];
#pragma unroll
      for (int cc = 0; cc < 16; cc++)
        acc[cc] = xr.x * sm.fill.w1s[cc] + xr.y * sm.fill.w1s[16 + cc] +
                  xr.z * sm.fill.w1s[32 + cc] + xr.w * sm.fill.w1s[48 + cc];
      H8 o0, o1;
#pragma unroll
      for (int q = 0; q < 4; q++) {
        o0.h2[q] = __float22half2_rn(make_float2(acc[2 * q] * dnv, acc[2 * q + 1] * dnv));
        o1.h2[q] = __float22half2_rn(make_float2(acc[8 + 2 * q] * dnv, acc[8 + 2 * q + 1] * dnv));
      }
      bufH[(size_t)node * 2] = o0.f4;
      bufH[(size_t)node * 2 + 1] = o1.f4;
    }
    __syncthreads();
    sm.fill.lpre[tid] = excl;
    __syncthreads();
    for (int j = e0 + tid; j < e1; j += 256) {
      int ed = ebuf[j];
      int p = atomicAdd(&sm.fill.lpre[ed & 255], 1);
      csr_src[e0 + p] = ed >> 8;
    }
    __syncthreads();
  }
  grid.sync();

  float* st1 = stats;       // [32]
  float* st2 = stats + 32;  // [64]
  float* st3 = stats + 96;  // [128]

  // Layer 1
  gather_phase<16, 1>((const float4*)bufH, row_start, csr_src, dinv, b1,
                      bufAct, partials, n, sm.red.redS, sm.red.redQ);
  grid.sync();
  reduce_phase(partials, st1, 32, nblk, sm.red.redS);
  grid.sync();

  // Layer 2
  mm_phase<16, 32>((const float4*)bufAct, st1, g1, bt1, W2, dinv, bufH, n,
                   sm.mm.w, sm.mm.bsc, sm.mm.bsh);
  grid.sync();
  gather_phase<32, 2>((const float4*)bufH, row_start, csr_src, dinv, b2,
                      bufAct, partials, n, sm.red.redS, sm.red.redQ);
  grid.sync();
  reduce_phase(partials, st2, 64, nblk, sm.red.redS);
  grid.sync();

  // Layer 3
  mm_phase<32, 64>((const float4*)bufAct, st2, g2, bt2, W3, dinv, bufH, n,
                   sm.mm.w, sm.mm.bsc, sm.mm.bsh);
  grid.sync();
  gather_phase<64, 3>((const float4*)bufH, row_start, csr_src, dinv, b3,
                      bufAct, partials, n, sm.red.redS, sm.red.redQ);
  grid.sync();
  reduce_phase(partials, st3, 128, nblk, sm.red.redS);
}

// ---------------- fused BN3+ELU + MLP head + log_softmax (2 threads/node) ----
__global__ __launch_bounds__(256) void head_kernel(
    const float4* __restrict__ h16,
    const float* __restrict__ st3, const float* __restrict__ g3,
    const float* __restrict__ bt3,
    const float* __restrict__ Wf1, const float* __restrict__ bf1,
    const float* __restrict__ Wf2, const float* __restrict__ bf2,
    const float* __restrict__ Wf3, const float* __restrict__ bf3,
    float* __restrict__ out, int n) {
  __shared__ float w1[64 * 32], w2[32 * 16], w3[32];
  __shared__ float sb1[32], sb2[16], sb3[2];
  __shared__ float bsc[64], bsh[64];
  __shared__ float a1s[32][128];
  __shared__ float a2s[16][128];
  int tid = threadIdx.x;
  for (int i = tid; i < 64 * 32; i += 256) w1[i] = Wf1[i];
  for (int i = tid; i < 32 * 16; i += 256) w2[i] = Wf2[i];
  if (tid < 64) {
    float inv_n = 1.0f / (float)n;
    float m = st3[tid] * inv_n;
    float var = fmaxf(st3[64 + tid] * inv_n - m * m, 0.f);
    float sc = rsqrtf(var + BN_EPS) * g3[tid];
    bsc[tid] = sc;
    bsh[tid] = bt3[tid] - m * sc;
  }
  if (tid < 32) {
    w3[tid] = Wf3[tid];
    sb1[tid] = bf1[tid];
  }
  if (tid < 16) sb2[tid] = bf2[tid];
  if (tid < 2) sb3[tid] = bf3[tid];
  __syncthreads();

  int node = tid & 127;
  int half = tid >> 7;
  int n0 = blockIdx.x * 128 + node;
  bool valid = (n0 < n);

  float a1[16];
#pragma unroll
  for (int c = 0; c < 16; c++) a1[c] = sb1[half * 16 + c];
  if (valid) {
    const float4* hrow = h16 + (size_t)n0 * 8;
#pragma unroll
    for (int j = 0; j < 8; j++) {
      H8 u;
      u.f4 = hrow[j];
#pragma unroll
      for (int q = 0; q < 4; q++) {
        float2 f = __half22float2(u.h2[q]);
        int k0 = j * 8 + 2 * q, k1 = k0 + 1;
        float v0 = f.x * bsc[k0] + bsh[k0];
        v0 = v0 > 0.f ? v0 : (__expf(v0) - 1.f);
        float v1 = f.y * bsc[k1] + bsh[k1];
        v1 = v1 > 0.f ? v1 : (__expf(v1) - 1.f);
#pragma unroll
        for (int c = 0; c < 16; c++)
          a1[c] += v0 * w1[k0 * 32 + half * 16 + c] + v1 * w1[k1 * 32 + half * 16 + c];
      }
    }
  }
#pragma unroll
  for (int c = 0; c < 16; c++) {
    float v = a1[c];
    a1s[half * 16 + c][node] = v > 0.f ? v : (__expf(v) - 1.f);
  }
  __syncthreads();

  float a2[8];
#pragma unroll
  for (int c = 0; c < 8; c++) a2[c] = sb2[half * 8 + c];
#pragma unroll
  for (int k = 0; k < 32; k++) {
    float ak = a1s[k][node];
#pragma unroll
    for (int c = 0; c < 8; c++) a2[c] += ak * w2[k * 16 + half * 8 + c];
  }
#pragma unroll
  for (int c = 0; c < 8; c++) {
    float v = a2[c];
    a2s[half * 8 + c][node] = v > 0.f ? v : (__expf(v) - 1.f);
  }
  __syncthreads();

  if (half == 0 && valid) {
    float z0 = sb3[0], z1 = sb3[1];
#pragma unroll
    for (int k = 0; k < 16; k++) {
      float ak = a2s[k][node];
      z0 += ak * w3[k * 2 + 0];
      z1 += ak * w3[k * 2 + 1];
    }
    float mx = fmaxf(z0, z1);
    float lse = mx + __logf(__expf(z0 - mx) + __expf(z1 - mx));
    out[(size_t)n0 * 2 + 0] = z0 - lse;
    out[(size_t)n0 * 2 + 1] = z1 - lse;
  }
}

// ---------------- launch ----------------

extern "C" void kernel_launch(void* const* d_in, const int* in_sizes, int n_in,
                              void* d_out, int out_size, void* d_ws, size_t ws_size,
                              hipStream_t stream) {
  const float* x = (const float*)d_in[0];
  const int* ei = (const int*)d_in[1];
  const float* W1 = (const float*)d_in[2];  const float* b1 = (const float*)d_in[3];
  const float* g1 = (const float*)d_in[4];  const float* bt1 = (const float*)d_in[5];
  const float* W2 = (const float*)d_in[6];  const float* b2 = (const float*)d_in[7];
  const float* g2 = (const float*)d_in[8];  const float* bt2 = (const float*)d_in[9];
  const float* W3 = (const float*)d_in[10]; const float* b3 = (const float*)d_in[11];
  const float* g3 = (const float*)d_in[12]; const float* bt3 = (const float*)d_in[13];
  const float* Wf1 = (const float*)d_in[14]; const float* bf1 = (const float*)d_in[15];
  const float* Wf2 = (const float*)d_in[16]; const float* bf2 = (const float*)d_in[17];
  const float* Wf3 = (const float*)d_in[18]; const float* bf3 = (const float*)d_in[19];
  float* out = (float*)d_out;

  int N = in_sizes[0] / 4;
  int E = in_sizes[1] / 2;
  const int* srcp = ei;
  const int* dstp = ei + E;
  int NBUCK = (N + 255) >> 8;

  char* ws = (char*)d_ws;
  size_t off = 0;
  auto alloc = [&](size_t bytes) {
    off = (off + 255) & ~(size_t)255;
    size_t o = off;
    off += bytes;
    return o;
  };
  float* dinv      = (float*)(ws + alloc((size_t)N * 4));
  int*   row_start = (int*)  (ws + alloc((size_t)(N + 1) * 4));
  int*   histpart  = (int*)  (ws + alloc((size_t)NHB * 512 * 4));
  float* stats     = (float*)(ws + alloc((size_t)224 * 4));
  int*   boffset   = (int*)  (ws + alloc((size_t)513 * 4));
  int*   bcursor   = (int*)  (ws + alloc((size_t)513 * 4));
  int*   csr_src   = (int*)  (ws + alloc((size_t)E * 4));
  float* partials  = (float*)(ws + alloc((size_t)2048 * 128 * 4));
  float4* bufH     = (float4*)(ws + alloc((size_t)N * 64 * 2));
  float4* bufAct   = (float4*)(ws + alloc((size_t)N * 64 * 2));
  int*   ebuf      = (int*)  (ws + alloc((size_t)E * 4));
  float* st3 = stats + 96;

  // cooperative grid: all blocks co-resident, clamped by occupancy
  int occ = 0;
  hipOccupancyMaxActiveBlocksPerMultiprocessor(&occ, (const void*)gcn_mega, 256, 0);
  if (occ <= 0) occ = 4;
  int nblk = occ * 256;  // 256 CUs
  if (nblk > 2048) nblk = 2048;

  void* args[] = {
      (void*)&x, (void*)&srcp, (void*)&dstp,
      (void*)&W1, (void*)&b1, (void*)&g1, (void*)&bt1,
      (void*)&W2, (void*)&b2, (void*)&g2, (void*)&bt2,
      (void*)&W3, (void*)&b3, (void*)&g3, (void*)&bt3,
      (void*)&dinv, (void*)&row_start, (void*)&histpart, (void*)&stats,
      (void*)&boffset, (void*)&bcursor, (void*)&csr_src, (void*)&partials,
      (void*)&bufH, (void*)&bufAct, (void*)&ebuf, (void*)&N, (void*)&E, (void*)&NBUCK};
  hipLaunchCooperativeKernel((const void*)gcn_mega, dim3(nblk), dim3(256), args, 0, stream);

  // head (separate: its 35KB LDS would halve mega occupancy)
  head_kernel<<<(N + 127) / 128, 256, 0, stream>>>(
      (const float4*)bufAct, st3, g3, bt3, Wf1, bf1, Wf2, bf2, Wf3, bf3, out, N);
}

// Round 16
// 201.005 us; speedup vs baseline: 7.6167x; 7.6167x over previous
//
#include <hip/hip_runtime.h>
#include <hip/hip_fp16.h>
#include <math.h>

#define BN_EPS 1e-5f

union H8 {  // 8 halfs = 16 bytes
  float4 f4;
  __half2 h2[4];
};

// ---------------- bucketed CSR build ----------------
// bucket b = dst >> 8 (256 nodes per bucket). NBUCK = ceil(N/256) <= 512.

#define NHB 512  // hist grid

__global__ void hist_kernel(const int* __restrict__ dst, int* __restrict__ histpart, int e) {
  __shared__ int h[512];
  for (int i = threadIdx.x; i < 512; i += 256) h[i] = 0;
  __syncthreads();
  int stride = gridDim.x * 256;
  for (int i = blockIdx.x * 256 + threadIdx.x; i < e; i += stride)
    atomicAdd(&h[dst[i] >> 8], 1);
  __syncthreads();
  for (int i = threadIdx.x; i < 512; i += 256)
    histpart[blockIdx.x * 512 + i] = h[i];
}

// one block, 512 threads: column-sum histpart -> scan -> boffset/bcursor.
__global__ void scan_buckets(const int* __restrict__ histpart,
                             int* __restrict__ boffset, int* __restrict__ bcursor,
                             int* __restrict__ row_start, int nbuck, int n, int e) {
  __shared__ int sc[512];
  int tid = threadIdx.x;
  int v = 0;
  for (int r = 0; r < NHB; r++) v += histpart[r * 512 + tid];  // coalesced rows
  sc[tid] = v;
  __syncthreads();
  for (int off = 1; off < 512; off <<= 1) {
    int add = (tid >= off) ? sc[tid - off] : 0;
    __syncthreads();
    sc[tid] += add;
    __syncthreads();
  }
  int excl = sc[tid] - v;
  if (tid <= nbuck) {
    int val = (tid < nbuck) ? excl : e;
    boffset[tid] = val;
    bcursor[tid] = val;
  }
  if (tid == 0) row_start[n] = e;
}

// each block owns a contiguous 4096-edge range; reserves per-bucket chunks and
// appends packed (src<<8 | dst&255) -> ebuf (one int per edge; src < 2^23).
__global__ void partition_kernel(const int* __restrict__ src, const int* __restrict__ dst,
                                 int* __restrict__ bcursor, int* __restrict__ ebuf, int e) {
  __shared__ int h[512];
  __shared__ int base[512];
  const int BLK_E = 4096;
  int e0 = blockIdx.x * BLK_E;
  int e1 = min(e0 + BLK_E, e);
  for (int i = threadIdx.x; i < 512; i += 256) h[i] = 0;
  __syncthreads();
  for (int i = e0 + threadIdx.x; i < e1; i += 256)
    atomicAdd(&h[dst[i] >> 8], 1);
  __syncthreads();
  for (int i = threadIdx.x; i < 512; i += 256) {
    int c = h[i];
    base[i] = (c > 0) ? atomicAdd(&bcursor[i], c) : 0;
    h[i] = 0;  // reuse as within-block rank
  }
  __syncthreads();
  for (int i = e0 + threadIdx.x; i < e1; i += 256) {
    int d = dst[i];
    int b = d >> 8;
    int r = atomicAdd(&h[b], 1);
    ebuf[base[b] + r] = (src[i] << 8) | (d & 255);
  }
}

// one block per bucket: LDS count+scan+cursor -> row_start, dinv, csr_src.
// FUSED layer-1 matmul: hh1[node] = fp16(dinv * x@W1)  (4->16, W1 in LDS).
__global__ void bucket_fill(const int* __restrict__ ebuf, const int* __restrict__ boffset,
                            const float* __restrict__ x, const float* __restrict__ W1,
                            int* __restrict__ row_start, float* __restrict__ dinv,
                            int* __restrict__ csr_src, float4* __restrict__ hh1, int n) {
  __shared__ int lcnt[256];
  __shared__ int lpre[256];
  __shared__ float w1s[64];
  int bid = blockIdx.x;
  int nb0 = bid << 8;
  int tid = threadIdx.x;
  int e0 = boffset[bid], e1 = boffset[bid + 1];
  lcnt[tid] = 0;
  if (tid < 64) w1s[tid] = W1[tid];
  __syncthreads();
  for (int j = e0 + tid; j < e1; j += 256)
    atomicAdd(&lcnt[ebuf[j] & 255], 1);
  __syncthreads();
  int v = lcnt[tid];
  lpre[tid] = v;
  __syncthreads();
  for (int off = 1; off < 256; off <<= 1) {
    int add = (tid >= off) ? lpre[tid - off] : 0;
    __syncthreads();
    lpre[tid] += add;
    __syncthreads();
  }
  int excl = lpre[tid] - v;
  int node = nb0 + tid;
  if (node < n) {
    row_start[node] = e0 + excl;
    float dnv = rsqrtf((float)(v + 1));  // +1 self loop
    dinv[node] = dnv;
    float4 xr = ((const float4*)x)[node];
    float acc[16];
#pragma unroll
    for (int c = 0; c < 16; c++)
      acc[c] = xr.x * w1s[c] + xr.y * w1s[16 + c] + xr.z * w1s[32 + c] + xr.w * w1s[48 + c];
    H8 o0, o1;
#pragma unroll
    for (int q = 0; q < 4; q++) {
      o0.h2[q] = __float22half2_rn(make_float2(acc[2 * q] * dnv, acc[2 * q + 1] * dnv));
      o1.h2[q] = __float22half2_rn(make_float2(acc[8 + 2 * q] * dnv, acc[8 + 2 * q + 1] * dnv));
    }
    hh1[(size_t)node * 2] = o0.f4;
    hh1[(size_t)node * 2 + 1] = o1.f4;
  }
  __syncthreads();
  lpre[tid] = excl;  // running cursor
  __syncthreads();
  for (int j = e0 + tid; j < e1; j += 256) {
    int ed = ebuf[j];
    int p = atomicAdd(&lpre[ed & 255], 1);
    csr_src[e0 + p] = ed >> 8;
  }
}

// ---------------- fused BN+ELU+matmul (fp16 in) -> fp16 hh ----------------
template <int K, int C>
__global__ __launch_bounds__(256) void mm_dinv_h(
    const float4* __restrict__ Xh, const float* __restrict__ stats,
    const float* __restrict__ g, const float* __restrict__ bt,
    const float* __restrict__ W, const float* __restrict__ dinv,
    float4* __restrict__ hh, int n) {
  constexpr int GP8 = C / 8;
  constexpr int KG8 = K / 8;
  __shared__ float w[K * C];
  __shared__ float bsc[K], bsh[K];
  for (int i = threadIdx.x; i < K * C; i += 256) w[i] = W[i];
  if (threadIdx.x < K) {
    int c = threadIdx.x;
    float inv_n = 1.0f / (float)n;
    float m = stats[c] * inv_n;
    float var = fmaxf(stats[K + c] * inv_n - m * m, 0.f);
    float sc = rsqrtf(var + BN_EPS) * g[c];
    bsc[c] = sc;
    bsh[c] = bt[c] - m * sc;
  }
  __syncthreads();

  int idx = blockIdx.x * 256 + threadIdx.x;
  if (idx >= n * GP8) return;
  int nn = idx / GP8;
  int c8 = idx % GP8;

  float acc[8];
#pragma unroll
  for (int t = 0; t < 8; t++) acc[t] = 0.f;

  const float4* rowh = Xh + (size_t)nn * KG8;
#pragma unroll
  for (int j8 = 0; j8 < KG8; j8++) {
    H8 u;
    u.f4 = rowh[j8];
#pragma unroll
    for (int q = 0; q < 4; q++) {
      float2 f = __half22float2(u.h2[q]);
      int k0 = j8 * 8 + 2 * q, k1 = k0 + 1;
      float v0 = f.x * bsc[k0] + bsh[k0];
      v0 = v0 > 0.f ? v0 : (__expf(v0) - 1.f);  // ELU
      float v1 = f.y * bsc[k1] + bsh[k1];
      v1 = v1 > 0.f ? v1 : (__expf(v1) - 1.f);
      int wb0 = k0 * C + c8 * 8, wb1 = k1 * C + c8 * 8;
#pragma unroll
      for (int t = 0; t < 8; t++) acc[t] += v0 * w[wb0 + t] + v1 * w[wb1 + t];
    }
  }
  float dn = dinv[nn];
  H8 o;
#pragma unroll
  for (int q = 0; q < 4; q++)
    o.h2[q] = __float22half2_rn(make_float2(acc[2 * q] * dn, acc[2 * q + 1] * dn));
  hh[idx] = o.f4;
}

// ---------------- gather (fp16 rows) + bias + ReLU -> fp16 act + stats partials --
template <int C, int LOGGP>
__global__ __launch_bounds__(256) void gather_finalize_h(
    const float4* __restrict__ hh8, const int* __restrict__ row_start,
    const int* __restrict__ csr_src, const float* __restrict__ dinv,
    const float* __restrict__ bias, float4* __restrict__ act4,
    float* __restrict__ partials, int n) {
  constexpr int GP = C / 8;
  constexpr int NPB = 256 / GP;
  int tid = threadIdx.x;
  int c8 = tid & (GP - 1);
  int local = tid >> LOGGP;
  int n0 = blockIdx.x * NPB + local;
  bool valid = (n0 < n);

  float vo[8];
#pragma unroll
  for (int t = 0; t < 8; t++) vo[t] = 0.f;

  if (valid) {
    float acc[8];
    {
      H8 u;
      u.f4 = hh8[(size_t)n0 * GP + c8];  // self term
#pragma unroll
      for (int q = 0; q < 4; q++) {
        float2 f = __half22float2(u.h2[q]);
        acc[2 * q] = f.x;
        acc[2 * q + 1] = f.y;
      }
    }
    int s = row_start[n0], e0 = row_start[n0 + 1];
    int j = s;
    for (; j + 8 <= e0; j += 8) {
      H8 u[8];
#pragma unroll
      for (int m = 0; m < 8; m++) u[m].f4 = hh8[(size_t)csr_src[j + m] * GP + c8];
#pragma unroll
      for (int m = 0; m < 8; m++)
#pragma unroll
        for (int q = 0; q < 4; q++) {
          float2 f = __half22float2(u[m].h2[q]);
          acc[2 * q] += f.x;
          acc[2 * q + 1] += f.y;
        }
    }
    for (; j + 4 <= e0; j += 4) {
      H8 u[4];
#pragma unroll
      for (int m = 0; m < 4; m++) u[m].f4 = hh8[(size_t)csr_src[j + m] * GP + c8];
#pragma unroll
      for (int m = 0; m < 4; m++)
#pragma unroll
        for (int q = 0; q < 4; q++) {
          float2 f = __half22float2(u[m].h2[q]);
          acc[2 * q] += f.x;
          acc[2 * q + 1] += f.y;
        }
    }
    for (; j < e0; j++) {
      H8 u;
      u.f4 = hh8[(size_t)csr_src[j] * GP + c8];
#pragma unroll
      for (int q = 0; q < 4; q++) {
        float2 f = __half22float2(u.h2[q]);
        acc[2 * q] += f.x;
        acc[2 * q + 1] += f.y;
      }
    }

    float dn = dinv[n0];
    const float4* bias4 = (const float4*)bias;
    float4 blo = bias4[c8 * 2], bhi = bias4[c8 * 2 + 1];
    vo[0] = fmaxf(dn * acc[0] + blo.x, 0.f);
    vo[1] = fmaxf(dn * acc[1] + blo.y, 0.f);
    vo[2] = fmaxf(dn * acc[2] + blo.z, 0.f);
    vo[3] = fmaxf(dn * acc[3] + blo.w, 0.f);
    vo[4] = fmaxf(dn * acc[4] + bhi.x, 0.f);
    vo[5] = fmaxf(dn * acc[5] + bhi.y, 0.f);
    vo[6] = fmaxf(dn * acc[6] + bhi.z, 0.f);
    vo[7] = fmaxf(dn * acc[7] + bhi.w, 0.f);
    H8 o;
#pragma unroll
    for (int q = 0; q < 4; q++)
      o.h2[q] = __float22half2_rn(make_float2(vo[2 * q], vo[2 * q + 1]));
    act4[(size_t)n0 * GP + c8] = o.f4;
  }

  // per-channel block reduce: sum & sumsq over 'local' (fp32, pre-rounding)
  __shared__ float redS[8 * 256];
  __shared__ float redQ[8 * 256];
#pragma unroll
  for (int t = 0; t < 8; t++) {
    redS[t * 256 + tid] = vo[t];
    redQ[t * 256 + tid] = vo[t] * vo[t];
  }
#pragma unroll
  for (int off = NPB / 2; off >= 1; off >>= 1) {
    __syncthreads();
    if (local < off) {
#pragma unroll
      for (int t = 0; t < 8; t++) {
        redS[t * 256 + tid] += redS[t * 256 + tid + off * GP];
        redQ[t * 256 + tid] += redQ[t * 256 + tid + off * GP];
      }
    }
  }
  __syncthreads();
  if (local == 0) {
#pragma unroll
    for (int t = 0; t < 8; t++) {
      partials[(size_t)blockIdx.x * 2 * C + c8 * 8 + t] = redS[t * 256 + tid];
      partials[(size_t)blockIdx.x * 2 * C + C + c8 * 8 + t] = redQ[t * 256 + tid];
    }
  }
}

// owner-write reduce: grid = C2 blocks; block ch sums partials[.][ch], stores.
template <int C2>
__global__ void reduce_partials(const float* __restrict__ partials,
                                float* __restrict__ stats, int rows) {
  int ch = blockIdx.x;
  float acc = 0.f;
  for (int r = threadIdx.x; r < rows; r += 256)
    acc += partials[(size_t)r * C2 + ch];
  __shared__ float red[256];
  red[threadIdx.x] = acc;
  __syncthreads();
#pragma unroll
  for (int off = 128; off >= 1; off >>= 1) {
    if (threadIdx.x < off) red[threadIdx.x] += red[threadIdx.x + off];
    __syncthreads();
  }
  if (threadIdx.x == 0) stats[ch] = red[0];
}

// ---------------- fused BN3+ELU + MLP head + log_softmax (2 threads/node) ----

__global__ __launch_bounds__(256) void head_kernel(
    const float4* __restrict__ h16,
    const float* __restrict__ st3, const float* __restrict__ g3,
    const float* __restrict__ bt3,
    const float* __restrict__ Wf1, const float* __restrict__ bf1,
    const float* __restrict__ Wf2, const float* __restrict__ bf2,
    const float* __restrict__ Wf3, const float* __restrict__ bf3,
    float* __restrict__ out, int n) {
  __shared__ float w1[64 * 32], w2[32 * 16], w3[32];
  __shared__ float sb1[32], sb2[16], sb3[2];
  __shared__ float bsc[64], bsh[64];
  __shared__ float a1s[32][128];
  __shared__ float a2s[16][128];
  int tid = threadIdx.x;
  for (int i = tid; i < 64 * 32; i += 256) w1[i] = Wf1[i];
  for (int i = tid; i < 32 * 16; i += 256) w2[i] = Wf2[i];
  if (tid < 64) {
    float inv_n = 1.0f / (float)n;
    float m = st3[tid] * inv_n;
    float var = fmaxf(st3[64 + tid] * inv_n - m * m, 0.f);
    float sc = rsqrtf(var + BN_EPS) * g3[tid];
    bsc[tid] = sc;
    bsh[tid] = bt3[tid] - m * sc;
  }
  if (tid < 32) {
    w3[tid] = Wf3[tid];
    sb1[tid] = bf1[tid];
  }
  if (tid < 16) sb2[tid] = bf2[tid];
  if (tid < 2) sb3[tid] = bf3[tid];
  __syncthreads();

  int node = tid & 127;
  int half = tid >> 7;
  int n0 = blockIdx.x * 128 + node;
  bool valid = (n0 < n);

  float a1[16];
#pragma unroll
  for (int c = 0; c < 16; c++) a1[c] = sb1[half * 16 + c];
  if (valid) {
    const float4* hrow = h16 + (size_t)n0 * 8;
#pragma unroll
    for (int j = 0; j < 8; j++) {
      H8 u;
      u.f4 = hrow[j];
#pragma unroll
      for (int q = 0; q < 4; q++) {
        float2 f = __half22float2(u.h2[q]);
        int k0 = j * 8 + 2 * q, k1 = k0 + 1;
        float v0 = f.x * bsc[k0] + bsh[k0];
        v0 = v0 > 0.f ? v0 : (__expf(v0) - 1.f);
        float v1 = f.y * bsc[k1] + bsh[k1];
        v1 = v1 > 0.f ? v1 : (__expf(v1) - 1.f);
#pragma unroll
        for (int c = 0; c < 16; c++)
          a1[c] += v0 * w1[k0 * 32 + half * 16 + c] + v1 * w1[k1 * 32 + half * 16 + c];
      }
    }
  }
#pragma unroll
  for (int c = 0; c < 16; c++) {
    float v = a1[c];
    a1s[half * 16 + c][node] = v > 0.f ? v : (__expf(v) - 1.f);
  }
  __syncthreads();

  float a2[8];
#pragma unroll
  for (int c = 0; c < 8; c++) a2[c] = sb2[half * 8 + c];
#pragma unroll
  for (int k = 0; k < 32; k++) {
    float ak = a1s[k][node];
#pragma unroll
    for (int c = 0; c < 8; c++) a2[c] += ak * w2[k * 16 + half * 8 + c];
  }
#pragma unroll
  for (int c = 0; c < 8; c++) {
    float v = a2[c];
    a2s[half * 8 + c][node] = v > 0.f ? v : (__expf(v) - 1.f);
  }
  __syncthreads();

  if (half == 0 && valid) {
    float z0 = sb3[0], z1 = sb3[1];
#pragma unroll
    for (int k = 0; k < 16; k++) {
      float ak = a2s[k][node];
      z0 += ak * w3[k * 2 + 0];
      z1 += ak * w3[k * 2 + 1];
    }
    float mx = fmaxf(z0, z1);
    float lse = mx + __logf(__expf(z0 - mx) + __expf(z1 - mx));
    out[(size_t)n0 * 2 + 0] = z0 - lse;
    out[(size_t)n0 * 2 + 1] = z1 - lse;
  }
}

// ---------------- launch ----------------

extern "C" void kernel_launch(void* const* d_in, const int* in_sizes, int n_in,
                              void* d_out, int out_size, void* d_ws, size_t ws_size,
                              hipStream_t stream) {
  const float* x = (const float*)d_in[0];
  const int* ei = (const int*)d_in[1];
  const float* W1 = (const float*)d_in[2];  const float* b1 = (const float*)d_in[3];
  const float* g1 = (const float*)d_in[4];  const float* bt1 = (const float*)d_in[5];
  const float* W2 = (const float*)d_in[6];  const float* b2 = (const float*)d_in[7];
  const float* g2 = (const float*)d_in[8];  const float* bt2 = (const float*)d_in[9];
  const float* W3 = (const float*)d_in[10]; const float* b3 = (const float*)d_in[11];
  const float* g3 = (const float*)d_in[12]; const float* bt3 = (const float*)d_in[13];
  const float* Wf1 = (const float*)d_in[14]; const float* bf1 = (const float*)d_in[15];
  const float* Wf2 = (const float*)d_in[16]; const float* bf2 = (const float*)d_in[17];
  const float* Wf3 = (const float*)d_in[18]; const float* bf3 = (const float*)d_in[19];
  float* out = (float*)d_out;

  const int N = in_sizes[0] / 4;
  const int E = in_sizes[1] / 2;
  const int* srcp = ei;
  const int* dstp = ei + E;
  const int NBUCK = (N + 255) >> 8;  // <= 512 for N <= 131072

  char* ws = (char*)d_ws;
  size_t off = 0;
  auto alloc = [&](size_t bytes) {
    off = (off + 255) & ~(size_t)255;
    size_t o = off;
    off += bytes;
    return o;
  };
  float* dinv      = (float*)(ws + alloc((size_t)N * 4));
  int*   row_start = (int*)  (ws + alloc((size_t)(N + 1) * 4));
  int*   histpart  = (int*)  (ws + alloc((size_t)NHB * 512 * 4));
  float* stats     = (float*)(ws + alloc((size_t)224 * 4));
  int*   boffset   = (int*)  (ws + alloc((size_t)513 * 4));
  int*   bcursor   = (int*)  (ws + alloc((size_t)513 * 4));
  int*   csr_src   = (int*)  (ws + alloc((size_t)E * 4));
  float* partials  = (float*)(ws + alloc((size_t)3200 * 128 * 4));  // max grid*2C
  float* bufH      = (float*)(ws + alloc((size_t)N * 64 * 2));  // fp16 hh
  float* bufAct    = (float*)(ws + alloc((size_t)N * 64 * 2));  // fp16 act
  float* st1 = stats;       // [32]
  float* st2 = stats + 32;  // [64]
  float* st3 = stats + 96;  // [128]
  // ebuf (E ints = 4.8 MB) aliases bufAct (12.8 MB): bucket_fill reads ebuf,
  // writes hh1 into bufH (distinct); bufAct first written by gather1.
  int*   ebuf = (int*)bufAct;

  // CSR build (bucketed, LDS-local, packed edges; layer-1 mm fused into fill)
  hist_kernel<<<NHB, 256, 0, stream>>>(dstp, histpart, E);
  scan_buckets<<<1, 512, 0, stream>>>(histpart, boffset, bcursor, row_start, NBUCK, N, E);
  partition_kernel<<<(E + 4095) / 4096, 256, 0, stream>>>(srcp, dstp, bcursor, ebuf, E);
  bucket_fill<<<NBUCK, 256, 0, stream>>>(ebuf, boffset, x, W1, row_start, dinv, csr_src,
                                         (float4*)bufH, N);

  // Layer 1: gather hh1 (fp16 [N,16]) -> act1 fp16 + stats
  int g1n = (N + 127) / 128;
  gather_finalize_h<16, 1><<<g1n, 256, 0, stream>>>(
      (const float4*)bufH, row_start, csr_src, dinv, b1, (float4*)bufAct, partials, N);
  reduce_partials<32><<<32, 256, 0, stream>>>(partials, st1, g1n);

  // Layer 2: BN1+ELU+mm 16->32 (fp16 in/out); gather -> act2 fp16 + stats
  int g2n = (N + 63) / 64;
  mm_dinv_h<16, 32><<<(N * 4 + 255) / 256, 256, 0, stream>>>(
      (const float4*)bufAct, st1, g1, bt1, W2, dinv, (float4*)bufH, N);
  gather_finalize_h<32, 2><<<g2n, 256, 0, stream>>>(
      (const float4*)bufH, row_start, csr_src, dinv, b2, (float4*)bufAct, partials, N);
  reduce_partials<64><<<64, 256, 0, stream>>>(partials, st2, g2n);

  // Layer 3: BN2+ELU+mm 32->64; gather -> act3 fp16 + stats
  int g3n = (N + 31) / 32;
  mm_dinv_h<32, 64><<<(N * 8 + 255) / 256, 256, 0, stream>>>(
      (const float4*)bufAct, st2, g2, bt2, W3, dinv, (float4*)bufH, N);
  gather_finalize_h<64, 3><<<g3n, 256, 0, stream>>>(
      (const float4*)bufH, row_start, csr_src, dinv, b3, (float4*)bufAct, partials, N);
  reduce_partials<128><<<128, 256, 0, stream>>>(partials, st3, g3n);

  // MLP head (+ fused BN3/ELU) + log_softmax, 2 threads/node
  head_kernel<<<(N + 127) / 128, 256, 0, stream>>>(
      (const float4*)bufAct, st3, g3, bt3, Wf1, bf1, Wf2, bf2, Wf3, bf3, out, N);
}